// Round 4
// baseline (576.147 us; speedup 1.0000x reference)
//
#include <hip/hip_runtime.h>
#include <math.h>

// WLN regressor, bf16-MFMA + async-LDS gather version.
//  - gather commutes with row-wise matmul: gather(X)@W == gather(X@W)
//  - kernel (W_na/W_sa path) only live at last depth; U1 update dead after depth 1
//  - GEMMs: MFMA 16x16x32 bf16, global_load_lds(16B) staging (m97 structure)
//  - gathers: all neighbor rows DMA'd to LDS up front (deep vmcnt pipeline),
//    bond scalars in SGPRs via readfirstlane, j-outer/k-inner consume

typedef unsigned short ushort_t;
typedef __attribute__((ext_vector_type(8))) short bf16x8;
typedef __attribute__((ext_vector_type(8))) unsigned short ushort8;
typedef __attribute__((ext_vector_type(4))) float f32x4;

static constexpr int Hh  = 300;
static constexpr int Hp  = 320;      // padded hidden (col dim & activation stride)
static constexpr int Bn  = 16;
static constexpr int Nn  = 2048;
static constexpr int Rn  = Bn * Nn;  // 32768 rows
static constexpr int NBn = 10;

// weight-region offsets (in ushorts, relative to wAf)
static constexpr size_t OFF_U2 = 320 * 96;
static constexpr size_t OFF_NA = OFF_U2 + 320 * 320;
static constexpr size_t OFF_SA = OFF_NA + 320 * 320;
static constexpr size_t OFF_U1 = OFF_SA + 320 * 320;
static constexpr int    W_ELEMS = (int)(OFF_U1 + 320 * 640);

__device__ __forceinline__ ushort_t f2bf(float x) {
    union { float f; unsigned u; } c; c.f = x;
    unsigned r = c.u + 0x7FFFu + ((c.u >> 16) & 1u);   // RNE
    return (ushort_t)(r >> 16);
}
__device__ __forceinline__ float bf2f(ushort_t h) {
    union { float f; unsigned u; } c; c.u = ((unsigned)h) << 16;
    return c.f;
}

// async global->LDS, 16B per lane. Per-lane dst must equal wavebase + lane*16.
__device__ __forceinline__ void stage16(const void* g, void* l) {
#if __has_builtin(__builtin_amdgcn_global_load_lds)
    __builtin_amdgcn_global_load_lds(
        (const __attribute__((address_space(1))) void*)g,
        (__attribute__((address_space(3))) void*)l, 16, 0, 0);
#else
    *(ushort8*)l = *(const ushort8*)g;
#endif
}

__device__ __forceinline__ float rfl_f(float v) {
    return __int_as_float(__builtin_amdgcn_readfirstlane(__float_as_int(v)));
}

// ---------------------------------------------------------------------------
// MFMA GEMM: C[r,n] = act( sum_k Asel[r,k]*Wt[n,k] (+bias[n]) ), C bf16 [R][320]
// BM=128, BN=64, BK=32; 256 threads = 4 waves, each wave 32x64.
// LDS linear (unpadded) for global_load_lds staging.
// ---------------------------------------------------------------------------
template<bool RELU, bool BIAS, bool CONCAT>
__global__ __launch_bounds__(256)
void mfma_gemm_k(const ushort_t* __restrict__ A, const ushort_t* __restrict__ A2,
                 int lda, int KP,
                 const ushort_t* __restrict__ Wt,
                 const float* __restrict__ bias,
                 ushort_t* __restrict__ C)
{
    __shared__ __attribute__((aligned(16))) ushort_t As[128 * 32];  // 8 KB
    __shared__ __attribute__((aligned(16))) ushort_t Bs[64 * 32];   // 4 KB

    const int t    = threadIdx.x;
    const int wv   = t >> 6;
    const int ln   = t & 63;
    const int lrow = ln & 15;
    const int lgrp = ln >> 4;
    const int rowBase = blockIdx.y * 128;
    const int nBase   = blockIdx.x * 64;

    f32x4 acc[2][4];
#pragma unroll
    for (int i = 0; i < 2; i++)
#pragma unroll
        for (int j = 0; j < 4; j++) acc[i][j] = (f32x4){0.f, 0.f, 0.f, 0.f};

    const int half = KP >> 1;

    for (int k0 = 0; k0 < KP; k0 += 32) {
        // stage A tile 128x32: 2 rounds x 16B/thread, DMA to LDS
#pragma unroll
        for (int e = 0; e < 2; e++) {
            int chunk = t + e * 256;           // 0..511
            int r = chunk >> 2, c = chunk & 3;
            int k = k0 + c * 8;
            const ushort_t* src;
            if (CONCAT && k >= half) src = A2 + (size_t)(rowBase + r) * lda + (k - half);
            else                     src = A  + (size_t)(rowBase + r) * lda + k;
            stage16(src, &As[(size_t)chunk * 8]);
        }
        // stage B tile 64x32: 1 round
        {
            int r = t >> 2, c = t & 3;
            stage16(Wt + (size_t)(nBase + r) * KP + k0 + c * 8, &Bs[(size_t)t * 8]);
        }
        __syncthreads();   // drains vmcnt -> LDS writes visible

        bf16x8 af[2], bfr[4];
#pragma unroll
        for (int mb = 0; mb < 2; mb++)
            af[mb] = *(const bf16x8*)&As[(wv * 32 + mb * 16 + lrow) * 32 + lgrp * 8];
#pragma unroll
        for (int nb = 0; nb < 4; nb++)
            bfr[nb] = *(const bf16x8*)&Bs[(nb * 16 + lrow) * 32 + lgrp * 8];
#pragma unroll
        for (int mb = 0; mb < 2; mb++)
#pragma unroll
            for (int nb = 0; nb < 4; nb++)
                acc[mb][nb] = __builtin_amdgcn_mfma_f32_16x16x32_bf16(
                    af[mb], bfr[nb], acc[mb][nb], 0, 0, 0);
        __syncthreads();
    }

    // epilogue: D layout col=lane&15, row=(lane>>4)*4+r
#pragma unroll
    for (int mb = 0; mb < 2; mb++) {
        int row0 = rowBase + wv * 32 + mb * 16 + lgrp * 4;
#pragma unroll
        for (int nb = 0; nb < 4; nb++) {
            int col = nBase + nb * 16 + lrow;
            float bv = 0.f;
            if (BIAS) bv = (col < Hh) ? bias[col] : 0.f;
#pragma unroll
            for (int r = 0; r < 4; r++) {
                float v = acc[mb][nb][r] + bv;
                if (RELU) v = v > 0.f ? v : 0.f;
                C[(size_t)(row0 + r) * Hp + col] = f2bf(v);
            }
        }
    }
}

// ---------------------------------------------------------------------------
// Gather. 8192 blocks x 4 waves = 1 node/wave.
// All <=10 neighbor atom rows DMA'd to LDS up front (global_load_lds, 40 lanes),
// all bond rows loaded to VGPR then readfirstlane'd to SGPRs. One vmcnt(0).
// Consume: j-outer (hoists 6 sWb reads), k-inner unrolled with uniform branch.
// ---------------------------------------------------------------------------
template<bool FINAL>
__global__ __launch_bounds__(256)
void gather_k(const ushort_t* __restrict__ Arow,   // bf16 [R][320]
              const ushort_t* __restrict__ Asa,    // FINAL only
              const float* __restrict__ bond,      // [B*M, 6] fp32
              const float* __restrict__ Wb,        // 6 x 300 fp32
              const float* __restrict__ bias,      // b_u2 (LABEL)
              const int*   __restrict__ ag,
              const int*   __restrict__ bg,
              const int*   __restrict__ nnb,
              const float* __restrict__ nmask,     // FINAL
              const float* __restrict__ Wout,      // FINAL
              void* __restrict__ outp)             // bf16 label [R][320] or f32 out[B]
{
    __shared__ float sWb[6 * Hp];
    __shared__ float sV[Hp];
    __shared__ __attribute__((aligned(16))) ushort_t sAtom[4][NBn][Hp];
    __shared__ float sdot[4];
    for (int i = threadIdx.x; i < 6 * Hp; i += 256) {
        int tt = i / Hp, h = i - tt * Hp;
        sWb[i] = (h < Hh) ? Wb[tt * Hh + h] : 0.f;
    }
    for (int i = threadIdx.x; i < Hp; i += 256) {
        float v = 0.f;
        if (i < Hh) v = FINAL ? Wout[i] : bias[i];
        sV[i] = v;
    }
    __syncthreads();

    const int wave = threadIdx.x >> 6;
    const int lane = threadIdx.x & 63;
    const int node = blockIdx.x * 4 + wave;
    const int b    = node >> 11;               // N = 2048
    const int nn   = nnb[node];
    const int base = node * NBn;
    const size_t arow0 = (size_t)(b << 11) * Hp;
    const size_t brow0 = (size_t)(b << 12) * 6;

    const int iav = ag[base + (lane < 10 ? lane : 9)];
    const int ibv = bg[base + (lane < 10 ? lane : 9)];

    // issue all bond loads (VGPR tmp) and all atom-row DMAs, then one wait
    float tmpc[NBn][6];
#pragma unroll
    for (int k = 0; k < NBn; k++) {
        if (k < nn) {
            int ibk = __shfl(ibv, k);
            const float* pf = bond + brow0 + (size_t)ibk * 6;
#pragma unroll
            for (int tt = 0; tt < 6; tt++) tmpc[k][tt] = pf[tt];
        }
    }
#pragma unroll
    for (int k = 0; k < NBn; k++) {
        if (k < nn) {
            int iak = __shfl(iav, k);
            const ushort_t* pa = Arow + arow0 + (size_t)iak * Hp;
            if (lane < 40)
                stage16(pa + (size_t)lane * 8, &sAtom[wave][k][lane * 8]);
        }
    }
    // bond scalars -> SGPR (wave-uniform), frees VGPRs
    float c[NBn][6];
#pragma unroll
    for (int k = 0; k < NBn; k++) {
        if (k < nn) {
#pragma unroll
            for (int tt = 0; tt < 6; tt++) c[k][tt] = rfl_f(tmpc[k][tt]);
        }
    }
    asm volatile("s_waitcnt vmcnt(0)" ::: "memory");

    float acc[5];
#pragma unroll
    for (int j = 0; j < 5; j++) {
        const int h = lane + j * 64;
        const float w0 = sWb[h],          w1 = sWb[Hp + h],     w2 = sWb[2 * Hp + h];
        const float w3 = sWb[3 * Hp + h], w4 = sWb[4 * Hp + h], w5 = sWb[5 * Hp + h];
        const float sv = FINAL ? 0.f : sV[h];
        float a = 0.f;
#pragma unroll
        for (int k = 0; k < NBn; k++) {
            if (k < nn) {                      // wave-uniform branch
                float av = bf2f(sAtom[wave][k][h]);
                float w  = c[k][0] * w0 + c[k][1] * w1 + c[k][2] * w2
                         + c[k][3] * w3 + c[k][4] * w4 + c[k][5] * w5;
                if (FINAL) {
                    a += av * w;
                } else {
                    float v = av + w + sv;
                    a += v > 0.f ? v : 0.f;
                }
            }
        }
        acc[j] = a;
    }

    if (FINAL) {
        const ushort_t* psa = Asa + (size_t)node * Hp + lane;
        float dot = 0.f;
#pragma unroll
        for (int j = 0; j < 5; j++) {
            int h = lane + j * 64;
            dot += acc[j] * bf2f(psa[j * 64]) * sV[h];
        }
        dot *= nmask[node];
#pragma unroll
        for (int off = 32; off > 0; off >>= 1) dot += __shfl_down(dot, off, 64);
        if (lane == 0) sdot[wave] = dot;
        __syncthreads();
        if (threadIdx.x == 0)                   // 4 nodes/block share batch b
            atomicAdd(&((float*)outp)[b], sdot[0] + sdot[1] + sdot[2] + sdot[3]);
    } else {
        ushort_t* pl = (ushort_t*)outp + (size_t)node * Hp + lane;
#pragma unroll
        for (int j = 0; j < 5; j++) {
            int h = lane + j * 64;
            pl[j * 64] = (h < Hh) ? f2bf(acc[j]) : (ushort_t)0;   // keep pads zero
        }
    }
}

// ---------------------------------------------------------------------------
__global__ void zero_k(ushort_t* __restrict__ p, int n)
{
    int i = blockIdx.x * 256 + threadIdx.x;
    if (i < n) p[i] = 0;
}

__global__ void cvt_atom_k(const float* __restrict__ src, ushort_t* __restrict__ dst)
{
    int idx = blockIdx.x * 256 + threadIdx.x;    // over R*96
    if (idx >= Rn * 96) return;
    int r = idx / 96, c = idx - r * 96;
    dst[idx] = (c < 82) ? f2bf(src[r * 82 + c]) : (ushort_t)0;
}

// all weight conversions in one launch; grid.y selects segment
__global__ void cvt_weights_k(const float* __restrict__ W_af,
                              const float* __restrict__ W_u2,
                              const float* __restrict__ W_na,
                              const float* __restrict__ W_sa,
                              const float* __restrict__ W_u1,
                              ushort_t* __restrict__ dst0)
{
    const float* src; int Ksrc, kbase, stride; size_t doff;
    switch (blockIdx.y) {
    case 0:  src = W_af;             Ksrc =  82; kbase = 0;   stride =  96; doff = 0;      break;
    case 1:  src = W_u2;             Ksrc = 300; kbase = 0;   stride = 320; doff = OFF_U2; break;
    case 2:  src = W_na;             Ksrc = 300; kbase = 0;   stride = 320; doff = OFF_NA; break;
    case 3:  src = W_sa;             Ksrc = 300; kbase = 0;   stride = 320; doff = OFF_SA; break;
    case 4:  src = W_u1;             Ksrc = 300; kbase = 0;   stride = 640; doff = OFF_U1; break;
    default: src = W_u1 + 300 * 300; Ksrc = 300; kbase = 320; stride = 640; doff = OFF_U1; break;
    }
    int idx = blockIdx.x * 256 + threadIdx.x;
    if (idx >= Ksrc * Hh) return;
    int k = idx / Hh, n = idx - k * Hh;
    dst0[doff + (size_t)n * stride + kbase + k] = f2bf(src[idx]);
}

__global__ void init_out_k(float* __restrict__ out, const float* __restrict__ b_out)
{
    if (threadIdx.x < Bn) out[threadIdx.x] = b_out[0];
}

// ---------------------------------------------------------------------------
extern "C" void kernel_launch(void* const* d_in, const int* in_sizes, int n_in,
                              void* d_out, int out_size, void* d_ws, size_t ws_size,
                              hipStream_t stream)
{
    const float* input_atom = (const float*)d_in[0];
    const float* input_bond = (const float*)d_in[1];
    const float* node_mask  = (const float*)d_in[2];
    const int*   atom_graph = (const int*)d_in[3];
    const int*   bond_graph = (const int*)d_in[4];
    const int*   num_nbs    = (const int*)d_in[5];
    const float* W_af       = (const float*)d_in[6];
    const float* W_na       = (const float*)d_in[7];
    const float* W_nb       = (const float*)d_in[8];
    const float* W_sa       = (const float*)d_in[9];
    const float* W_u2       = (const float*)d_in[10];
    const float* b_u2       = (const float*)d_in[11];
    const float* W_u1       = (const float*)d_in[12];
    const float* b_u1       = (const float*)d_in[13];
    const float* W_out      = (const float*)d_in[14];
    const float* b_out      = (const float*)d_in[15];
    float* out = (float*)d_out;

    const float* W_u2b = W_u2 + (size_t)Hh * Hh;   // rows 300..305 (bond part)

    const size_t S2 = (size_t)Rn * Hp;             // bf16 elems per activation buffer
    ushort_t* bufA0 = (ushort_t*)d_ws;
    ushort_t* bufA1 = bufA0 + S2;
    ushort_t* bufP  = bufA1 + S2;                  // A_u2 / A_na projections
    ushort_t* bufL  = bufP  + S2;                  // nei_label
    ushort_t* bufS  = bufL  + S2;                  // A_sa
    ushort_t* iaB   = bufS  + S2;                  // input_atom bf16 [R][96]
    ushort_t* wAf   = iaB + (size_t)Rn * 96;       // weight region base

    zero_k<<<(W_ELEMS + 255) / 256, 256, 0, stream>>>(wAf, W_ELEMS);
    cvt_atom_k<<<(Rn * 96 + 255) / 256, 256, 0, stream>>>(input_atom, iaB);
    cvt_weights_k<<<dim3(352, 6), 256, 0, stream>>>(W_af, W_u2, W_na, W_sa, W_u1, wAf);
    init_out_k<<<dim3(1), dim3(64), 0, stream>>>(out, b_out);

    dim3 gg(5, Rn / 128);                          // 5 col tiles x 256 row tiles
    const int gb = Rn / 4;                         // 8192 gather blocks, 1 node/wave

    mfma_gemm_k<true, false, false><<<gg, 256, 0, stream>>>(
        iaB, nullptr, 96, 96, wAf, nullptr, bufA0);

    ushort_t* cur = bufA0;
    ushort_t* oth = bufA1;
    for (int d = 0; d < 2; d++) {
        mfma_gemm_k<false, false, false><<<gg, 256, 0, stream>>>(
            cur, nullptr, Hp, Hp, wAf + OFF_U2, nullptr, bufP);
        gather_k<false><<<gb, 256, 0, stream>>>(
            bufP, nullptr, input_bond, W_u2b, b_u2,
            atom_graph, bond_graph, num_nbs, nullptr, nullptr, bufL);
        mfma_gemm_k<true, true, true><<<gg, 256, 0, stream>>>(
            cur, bufL, Hp, 2 * Hp, wAf + OFF_U1, b_u1, oth);
        ushort_t* tmp = cur; cur = oth; oth = tmp;
    }

    // depth 2: only the kernel output is live
    mfma_gemm_k<false, false, false><<<gg, 256, 0, stream>>>(
        cur, nullptr, Hp, Hp, wAf + OFF_NA, nullptr, bufP);
    mfma_gemm_k<false, false, false><<<gg, 256, 0, stream>>>(
        cur, nullptr, Hp, Hp, wAf + OFF_SA, nullptr, bufS);
    gather_k<true><<<gb, 256, 0, stream>>>(
        bufP, bufS, input_bond, W_nb, nullptr,
        atom_graph, bond_graph, num_nbs, node_mask, W_out, out);
}

// Round 5
// 504.803 us; speedup vs baseline: 1.1413x; 1.1413x over previous
//
#include <hip/hip_runtime.h>
#include <math.h>

// WLN regressor, bf16-MFMA + XCD-localized gather version.
//  - gather commutes with row-wise matmul: gather(X)@W == gather(X@W)
//  - kernel (W_na/W_sa path) only live at last depth; U1 update dead after depth 1
//  - ALL blocks XCD-swizzled so batch b lives on XCD b%8: per-batch working set
//    (1.25 MB) stays L2-resident; producer GEMM and consumer gather share an XCD
//  - gather: 1 node/wave, all neighbor rows DMA'd to LDS (global_load_lds),
//    bond scalars in SGPRs, label stores non-temporal (don't evict gather set)

typedef unsigned short ushort_t;
typedef __attribute__((ext_vector_type(8))) short bf16x8;
typedef __attribute__((ext_vector_type(8))) unsigned short ushort8;
typedef __attribute__((ext_vector_type(4))) float f32x4;

static constexpr int Hh  = 300;
static constexpr int Hp  = 320;      // padded hidden (col dim & activation stride)
static constexpr int Bn  = 16;
static constexpr int Nn  = 2048;
static constexpr int Rn  = Bn * Nn;  // 32768 rows
static constexpr int NBn = 10;

// weight-region offsets (in ushorts, relative to wAf)
static constexpr size_t OFF_U2 = 320 * 96;
static constexpr size_t OFF_NA = OFF_U2 + 320 * 320;
static constexpr size_t OFF_SA = OFF_NA + 320 * 320;
static constexpr size_t OFF_U1 = OFF_SA + 320 * 320;
static constexpr int    W_ELEMS = (int)(OFF_U1 + 320 * 640);

__device__ __forceinline__ ushort_t f2bf(float x) {
    union { float f; unsigned u; } c; c.f = x;
    unsigned r = c.u + 0x7FFFu + ((c.u >> 16) & 1u);   // RNE
    return (ushort_t)(r >> 16);
}
__device__ __forceinline__ float bf2f(ushort_t h) {
    union { float f; unsigned u; } c; c.u = ((unsigned)h) << 16;
    return c.f;
}

// async global->LDS, 16B per lane (dst = wave base + lane*16)
__device__ __forceinline__ void stage16(const void* g, void* l) {
    __builtin_amdgcn_global_load_lds(
        (const __attribute__((address_space(1))) void*)g,
        (__attribute__((address_space(3))) void*)l, 16, 0, 0);
}

__device__ __forceinline__ float rfl_f(float v) {
    return __int_as_float(__builtin_amdgcn_readfirstlane(__float_as_int(v)));
}

// ---------------------------------------------------------------------------
// MFMA GEMM (R3 structure): C[r,n] = act(sum_k Asel[r,k]*Wt[n,k] (+bias[n]))
// BM=256, BN=64, BK=32; 256 threads = 4 waves, each wave 64x64.
// 1D grid of 640 blocks, XCD-swizzled: batch b -> XCD b%8.
// LDS rows padded to 40 bf16 (80B) -> worst 2-way bank conflict (free).
// ---------------------------------------------------------------------------
template<bool RELU, bool BIAS, bool CONCAT>
__global__ __launch_bounds__(256)
void mfma_gemm_k(const ushort_t* __restrict__ A, const ushort_t* __restrict__ A2,
                 int lda, int KP,
                 const ushort_t* __restrict__ Wt,
                 const float* __restrict__ bias,
                 ushort_t* __restrict__ C)
{
    __shared__ __attribute__((aligned(16))) ushort_t As[256 * 40];
    __shared__ __attribute__((aligned(16))) ushort_t Bs[64 * 40];

    // XCD swizzle: 640 blocks = 8 xcd * (2 batch * 8 rowtile * 5 col)
    const int id   = blockIdx.x;
    const int xcd  = id & 7;
    const int slot = id >> 3;            // 0..79
    const int bsel = slot / 40;          // 0..1
    const int sub  = slot % 40;
    const int batch = xcd + 8 * bsel;    // 0..15
    const int rowBase = (batch * 8 + sub / 5) * 256;
    const int nBase   = (sub % 5) * 64;

    const int t   = threadIdx.x;
    const int wv  = t >> 6;
    const int ln  = t & 63;
    const int lrow = ln & 15;
    const int lgrp = ln >> 4;

    f32x4 acc[4][4];
#pragma unroll
    for (int i = 0; i < 4; i++)
#pragma unroll
        for (int j = 0; j < 4; j++) acc[i][j] = (f32x4){0.f, 0.f, 0.f, 0.f};

    const int half = KP >> 1;

    for (int k0 = 0; k0 < KP; k0 += 32) {
#pragma unroll
        for (int e = 0; e < 4; e++) {
            int chunk = t + e * 256;
            int r = chunk >> 2, c = chunk & 3;
            int k = k0 + c * 8;
            const ushort_t* src;
            if (CONCAT && k >= half) src = A2 + (size_t)(rowBase + r) * lda + (k - half);
            else                     src = A  + (size_t)(rowBase + r) * lda + k;
            *(ushort8*)&As[r * 40 + c * 8] = *(const ushort8*)src;
        }
        {
            int r = t >> 2, c = t & 3;
            *(ushort8*)&Bs[r * 40 + c * 8] =
                *(const ushort8*)(Wt + (size_t)(nBase + r) * KP + k0 + c * 8);
        }
        __syncthreads();

        bf16x8 af[4], bfr[4];
#pragma unroll
        for (int mb = 0; mb < 4; mb++)
            af[mb] = *(const bf16x8*)&As[(wv * 64 + mb * 16 + lrow) * 40 + lgrp * 8];
#pragma unroll
        for (int nb = 0; nb < 4; nb++)
            bfr[nb] = *(const bf16x8*)&Bs[(nb * 16 + lrow) * 40 + lgrp * 8];
#pragma unroll
        for (int mb = 0; mb < 4; mb++)
#pragma unroll
            for (int nb = 0; nb < 4; nb++)
                acc[mb][nb] = __builtin_amdgcn_mfma_f32_16x16x32_bf16(
                    af[mb], bfr[nb], acc[mb][nb], 0, 0, 0);
        __syncthreads();
    }

    // epilogue: D layout col=lane&15, row=(lane>>4)*4+r
#pragma unroll
    for (int mb = 0; mb < 4; mb++) {
        int row0 = rowBase + wv * 64 + mb * 16 + lgrp * 4;
#pragma unroll
        for (int nb = 0; nb < 4; nb++) {
            int col = nBase + nb * 16 + lrow;
            float bv = 0.f;
            if (BIAS) bv = (col < Hh) ? bias[col] : 0.f;
#pragma unroll
            for (int r = 0; r < 4; r++) {
                float v = acc[mb][nb][r] + bv;
                if (RELU) v = v > 0.f ? v : 0.f;
                C[(size_t)(row0 + r) * Hp + col] = f2bf(v);
            }
        }
    }
}

// ---------------------------------------------------------------------------
// Gather. 8192 blocks (XCD-swizzled) x 4 waves = 1 node/wave.
// All <=10 neighbor atom rows DMA'd to LDS up front; bond scalars -> SGPRs.
// Label stores non-temporal (streamed; keep L2 for the gather-hot rows).
// ---------------------------------------------------------------------------
template<bool FINAL>
__global__ __launch_bounds__(256)
void gather_k(const ushort_t* __restrict__ Arow,   // bf16 [R][320]
              const ushort_t* __restrict__ Asa,    // FINAL only
              const float* __restrict__ bond,      // [B*M, 6] fp32
              const float* __restrict__ Wb,        // 6 x 300 fp32
              const float* __restrict__ bias,      // b_u2 (LABEL)
              const int*   __restrict__ ag,
              const int*   __restrict__ bg,
              const int*   __restrict__ nnb,
              const float* __restrict__ nmask,     // FINAL
              const float* __restrict__ Wout,      // FINAL
              void* __restrict__ outp)             // bf16 label [R][320] or f32 out[B]
{
    __shared__ float sWb[6 * Hp];
    __shared__ float sV[Hp];
    __shared__ __attribute__((aligned(16))) ushort_t sAtom[4][NBn][Hp];
    __shared__ float sdot[4];
    for (int i = threadIdx.x; i < 6 * Hp; i += 256) {
        int tt = i / Hp, h = i - tt * Hp;
        sWb[i] = (h < Hh) ? Wb[tt * Hh + h] : 0.f;
    }
    for (int i = threadIdx.x; i < Hp; i += 256) {
        float v = 0.f;
        if (i < Hh) v = FINAL ? Wout[i] : bias[i];
        sV[i] = v;
    }
    __syncthreads();

    const int wave = threadIdx.x >> 6;
    const int lane = threadIdx.x & 63;

    // XCD swizzle: 8192 blocks = 8 xcd * (2 batch * 512 node-groups)
    const int id  = blockIdx.x;
    const int xcd = id & 7;
    const int r_  = id >> 3;                   // 0..1023
    const int b   = xcd + 8 * (r_ & 1);        // batch 0..15 -> XCD b%8
    const int grp = r_ >> 1;                   // 0..511
    const int node = b * Nn + grp * 4 + wave;

    const int nn   = nnb[node];
    const int base = node * NBn;
    const size_t arow0 = (size_t)(b << 11) * Hp;
    const size_t brow0 = (size_t)(b << 12) * 6;

    const int iav = ag[base + (lane < 10 ? lane : 9)];
    const int ibv = bg[base + (lane < 10 ? lane : 9)];

    // issue all bond loads (VGPR tmp) and all atom-row DMAs, then one wait
    float tmpc[NBn][6];
#pragma unroll
    for (int k = 0; k < NBn; k++) {
        if (k < nn) {
            int ibk = __shfl(ibv, k);
            const float* pf = bond + brow0 + (size_t)ibk * 6;
#pragma unroll
            for (int tt = 0; tt < 6; tt++) tmpc[k][tt] = pf[tt];
        }
    }
#pragma unroll
    for (int k = 0; k < NBn; k++) {
        if (k < nn) {
            int iak = __shfl(iav, k);
            const ushort_t* pa = Arow + arow0 + (size_t)iak * Hp;
            if (lane < 40)
                stage16(pa + (size_t)lane * 8, &sAtom[wave][k][lane * 8]);
        }
    }
    float c[NBn][6];
#pragma unroll
    for (int k = 0; k < NBn; k++) {
        if (k < nn) {
#pragma unroll
            for (int tt = 0; tt < 6; tt++) c[k][tt] = rfl_f(tmpc[k][tt]);
        }
    }
    asm volatile("s_waitcnt vmcnt(0)" ::: "memory");

    float acc[5];
#pragma unroll
    for (int j = 0; j < 5; j++) {
        const int h = lane + j * 64;
        const float w0 = sWb[h],          w1 = sWb[Hp + h],     w2 = sWb[2 * Hp + h];
        const float w3 = sWb[3 * Hp + h], w4 = sWb[4 * Hp + h], w5 = sWb[5 * Hp + h];
        const float sv = FINAL ? 0.f : sV[h];
        float a = 0.f;
#pragma unroll
        for (int k = 0; k < NBn; k++) {
            if (k < nn) {                      // wave-uniform branch
                float av = bf2f(sAtom[wave][k][h]);
                float w  = c[k][0] * w0 + c[k][1] * w1 + c[k][2] * w2
                         + c[k][3] * w3 + c[k][4] * w4 + c[k][5] * w5;
                if (FINAL) {
                    a += av * w;
                } else {
                    float v = av + w + sv;
                    a += v > 0.f ? v : 0.f;
                }
            }
        }
        acc[j] = a;
    }

    if (FINAL) {
        const ushort_t* psa = Asa + (size_t)node * Hp + lane;
        float dot = 0.f;
#pragma unroll
        for (int j = 0; j < 5; j++) {
            int h = lane + j * 64;
            dot += acc[j] * bf2f(psa[j * 64]) * sV[h];
        }
        dot *= nmask[node];
#pragma unroll
        for (int off = 32; off > 0; off >>= 1) dot += __shfl_down(dot, off, 64);
        if (lane == 0) sdot[wave] = dot;
        __syncthreads();
        if (threadIdx.x == 0)                   // 4 nodes/block share batch b
            atomicAdd(&((float*)outp)[b], sdot[0] + sdot[1] + sdot[2] + sdot[3]);
    } else {
        ushort_t* pl = (ushort_t*)outp + (size_t)node * Hp + lane;
#pragma unroll
        for (int j = 0; j < 5; j++) {
            int h = lane + j * 64;
            ushort_t v = (h < Hh) ? f2bf(acc[j]) : (ushort_t)0;
            __builtin_nontemporal_store(v, pl + j * 64);
        }
    }
}

// ---------------------------------------------------------------------------
__global__ void zero_k(ushort_t* __restrict__ p, int n)
{
    int i = blockIdx.x * 256 + threadIdx.x;
    if (i < n) p[i] = 0;
}

__global__ void cvt_atom_k(const float* __restrict__ src, ushort_t* __restrict__ dst)
{
    int idx = blockIdx.x * 256 + threadIdx.x;    // over R*96
    if (idx >= Rn * 96) return;
    int r = idx / 96, c = idx - r * 96;
    dst[idx] = (c < 82) ? f2bf(src[r * 82 + c]) : (ushort_t)0;
}

// all weight conversions in one launch; grid.y selects segment
__global__ void cvt_weights_k(const float* __restrict__ W_af,
                              const float* __restrict__ W_u2,
                              const float* __restrict__ W_na,
                              const float* __restrict__ W_sa,
                              const float* __restrict__ W_u1,
                              ushort_t* __restrict__ dst0)
{
    const float* src; int Ksrc, kbase, stride; size_t doff;
    switch (blockIdx.y) {
    case 0:  src = W_af;             Ksrc =  82; kbase = 0;   stride =  96; doff = 0;      break;
    case 1:  src = W_u2;             Ksrc = 300; kbase = 0;   stride = 320; doff = OFF_U2; break;
    case 2:  src = W_na;             Ksrc = 300; kbase = 0;   stride = 320; doff = OFF_NA; break;
    case 3:  src = W_sa;             Ksrc = 300; kbase = 0;   stride = 320; doff = OFF_SA; break;
    case 4:  src = W_u1;             Ksrc = 300; kbase = 0;   stride = 640; doff = OFF_U1; break;
    default: src = W_u1 + 300 * 300; Ksrc = 300; kbase = 320; stride = 640; doff = OFF_U1; break;
    }
    int idx = blockIdx.x * 256 + threadIdx.x;
    if (idx >= Ksrc * Hh) return;
    int k = idx / Hh, n = idx - k * Hh;
    dst0[doff + (size_t)n * stride + kbase + k] = f2bf(src[idx]);
}

__global__ void init_out_k(float* __restrict__ out, const float* __restrict__ b_out)
{
    if (threadIdx.x < Bn) out[threadIdx.x] = b_out[0];
}

// ---------------------------------------------------------------------------
extern "C" void kernel_launch(void* const* d_in, const int* in_sizes, int n_in,
                              void* d_out, int out_size, void* d_ws, size_t ws_size,
                              hipStream_t stream)
{
    const float* input_atom = (const float*)d_in[0];
    const float* input_bond = (const float*)d_in[1];
    const float* node_mask  = (const float*)d_in[2];
    const int*   atom_graph = (const int*)d_in[3];
    const int*   bond_graph = (const int*)d_in[4];
    const int*   num_nbs    = (const int*)d_in[5];
    const float* W_af       = (const float*)d_in[6];
    const float* W_na       = (const float*)d_in[7];
    const float* W_nb       = (const float*)d_in[8];
    const float* W_sa       = (const float*)d_in[9];
    const float* W_u2       = (const float*)d_in[10];
    const float* b_u2       = (const float*)d_in[11];
    const float* W_u1       = (const float*)d_in[12];
    const float* b_u1       = (const float*)d_in[13];
    const float* W_out      = (const float*)d_in[14];
    const float* b_out      = (const float*)d_in[15];
    float* out = (float*)d_out;

    const float* W_u2b = W_u2 + (size_t)Hh * Hh;   // rows 300..305 (bond part)

    const size_t S2 = (size_t)Rn * Hp;             // bf16 elems per activation buffer
    ushort_t* bufA0 = (ushort_t*)d_ws;
    ushort_t* bufA1 = bufA0 + S2;
    ushort_t* bufP  = bufA1 + S2;                  // A_u2 / A_na projections
    ushort_t* bufL  = bufP  + S2;                  // nei_label
    ushort_t* bufS  = bufL  + S2;                  // A_sa
    ushort_t* iaB   = bufS  + S2;                  // input_atom bf16 [R][96]
    ushort_t* wAf   = iaB + (size_t)Rn * 96;       // weight region base

    zero_k<<<(W_ELEMS + 255) / 256, 256, 0, stream>>>(wAf, W_ELEMS);
    cvt_atom_k<<<(Rn * 96 + 255) / 256, 256, 0, stream>>>(input_atom, iaB);
    cvt_weights_k<<<dim3(352, 6), 256, 0, stream>>>(W_af, W_u2, W_na, W_sa, W_u1, wAf);
    init_out_k<<<dim3(1), dim3(64), 0, stream>>>(out, b_out);

    const int gemmBlocks = 640;                    // 8 xcd * 2 batch * 8 rt * 5 col
    const int gb = Rn / 4;                         // 8192 gather blocks, 1 node/wave

    mfma_gemm_k<true, false, false><<<gemmBlocks, 256, 0, stream>>>(
        iaB, nullptr, 96, 96, wAf, nullptr, bufA0);

    ushort_t* cur = bufA0;
    ushort_t* oth = bufA1;
    for (int d = 0; d < 2; d++) {
        mfma_gemm_k<false, false, false><<<gemmBlocks, 256, 0, stream>>>(
            cur, nullptr, Hp, Hp, wAf + OFF_U2, nullptr, bufP);
        gather_k<false><<<gb, 256, 0, stream>>>(
            bufP, nullptr, input_bond, W_u2b, b_u2,
            atom_graph, bond_graph, num_nbs, nullptr, nullptr, bufL);
        mfma_gemm_k<true, true, true><<<gemmBlocks, 256, 0, stream>>>(
            cur, bufL, Hp, 2 * Hp, wAf + OFF_U1, b_u1, oth);
        ushort_t* tmp = cur; cur = oth; oth = tmp;
    }

    // depth 2: only the kernel output is live
    mfma_gemm_k<false, false, false><<<gemmBlocks, 256, 0, stream>>>(
        cur, nullptr, Hp, Hp, wAf + OFF_NA, nullptr, bufP);
    mfma_gemm_k<false, false, false><<<gemmBlocks, 256, 0, stream>>>(
        cur, nullptr, Hp, Hp, wAf + OFF_SA, nullptr, bufS);
    gather_k<true><<<gb, 256, 0, stream>>>(
        bufP, bufS, input_bond, W_nb, nullptr,
        atom_graph, bond_graph, num_nbs, node_mask, W_out, out);
}